// Round 9
// baseline (87.556 us; speedup 1.0000x reference)
//
#include <hip/hip_runtime.h>
#include <math.h>

// MAM dense: C[i,j] = max_k(A[i,k]*W[j,k]) + min_k(A[i,k]*W[j,k]) + bias[j]
// A = x flat [M=2048, K=768]; W [N=768, K=768] row-major; out [M,N] f32.
// fp16 packed math (3 pk ops per 2 products = algebraic floor).
// R8 diagnosis: latency-bound at 3 waves/SIMD, LDS pipe 35us > VALU 23us.
// This round: K-split x4 (512-thr blocks, 4 k-groups of 128) -> 6 waves/SIMD,
// TM=4xTN=4 register tile -> LDS read bytes cut 1/3 (2 b128 per 16 outputs).
// Group partials combined via 2-round LDS tree. XOR row-swizzle on LDS tiles:
// writes 2-way (free), reads broadcast/conflict-free.

#define M_DIM 2048
#define N_DIM 768
#define K_DIM 768

#define BM 64
#define BN 32
#define BK 64
#define KP 32                  // k-pair rows per tile
#define NTILES 12

#define SAH 68                 // A row stride (h2 units); 68*4B: b128-aligned
#define SBH 36                 // B row stride (h2 units)
#define ASZ (KP * SAH)         // 2176 h2 per A buffer
#define BSZ (KP * SBH)         // 1152 h2 per B buffer
#define EPI_STRIDE 36          // floats per lid in epilogue region
#define EPI_REGION (128 * EPI_STRIDE)   // 4608 floats

typedef _Float16 h2 __attribute__((ext_vector_type(2)));   // 4 B
typedef _Float16 h8 __attribute__((ext_vector_type(8)));   // 16 B

__device__ __forceinline__ h2 cvt_pk(float x, float y) {
    return __builtin_bit_cast(h2, __builtin_amdgcn_cvt_pkrtz(x, y));
}
__device__ __forceinline__ h2 h2max(h2 a, h2 b) { return __builtin_elementwise_max(a, b); }
__device__ __forceinline__ h2 h2min(h2 a, h2 b) { return __builtin_elementwise_min(a, b); }

__global__ __launch_bounds__(512, 6) void mam_kernel(
    const float* __restrict__ A, const float* __restrict__ W,
    const float* __restrict__ bias, float* __restrict__ out)
{
    // union: staging (26624 B) / epilogue tree (36864 B)
    __shared__ __align__(16) unsigned char smem[36864];
    h2* Ash = (h2*)smem;                      // [2][ASZ]
    h2* Bsh = (h2*)(smem + 2 * ASZ * 4);      // [2][BSZ]
    float* epi = (float*)smem;                // [2][EPI_REGION]

    const int tid = threadIdx.x;
    const int g   = tid >> 7;        // k-group 0..3 (wave-uniform)
    const int lid = tid & 127;
    const int mt  = lid >> 3;        // 0..15 -> rows mt*4..mt*4+3
    const int nt  = lid & 7;         // 0..7  -> cols nt*4..nt*4+3
    const int m0 = blockIdx.y * BM;
    const int n0 = blockIdx.x * BN;

    h2 pmax[4][4], pmin[4][4];
    const _Float16 HMIN = (_Float16)(-65504.0f), HMAX = (_Float16)(65504.0f);
#pragma unroll
    for (int i = 0; i < 4; ++i)
#pragma unroll
        for (int j = 0; j < 4; ++j) {
            pmax[i][j] = (h2){HMIN, HMIN};
            pmin[i][j] = (h2){HMAX, HMAX};
        }

    // ---- staging map (512 threads): A 2 chunks, B 1 chunk of float4 ----
    const int arow = tid >> 4;                 // 0..31
    const int akc  = tid & 15;                 // k-chunk -> kk2 = 2*akc (+1)
    const int aswz = 4 * (akc & 7);            // XOR row-swizzle, bits 2..4
    const int awr  = arow ^ aswz;              // swizzled write row
    const float* Ap = A + (size_t)(m0 + arow) * K_DIM + akc * 4;
    const float* Wp = W + (size_t)(n0 + arow) * K_DIM + akc * 4;

    const float4 bv = *(const float4*)(bias + n0 + nt * 4);

    // ---- read offsets (h2 units), swizzle matched to writes:
    // kk2 = g*8 + 2u + o; kk2>>1 = g*4+u -> c = 4*((g*4+u)&7)
    unsigned aoff[4], boff[4];
#pragma unroll
    for (int u = 0; u < 4; ++u) {
        const int c = 4 * (((g << 2) + u) & 7);
        aoff[u] = (unsigned)((g * 8 + 2 * u) * SAH + ((4 * mt) ^ c));
        boff[u] = (unsigned)((g * 8 + 2 * u) * SBH + ((4 * nt) ^ c));
    }

    float4 pa0, pa1, pb0;

#define GLOAD(t) do {                                                         \
        const float* An_ = Ap + (t) * BK;                                     \
        pa0 = *(const float4*)(An_);                                          \
        pa1 = *(const float4*)(An_ + (size_t)32 * K_DIM);                     \
        pb0 = *(const float4*)(Wp + (t) * BK);                                \
    } while (0)

#define SWRITE(buf) do {                                                      \
        h2* Aw_ = Ash + (buf) * ASZ + 2 * akc * SAH + awr;                    \
        Aw_[0]        = cvt_pk(pa0.x, pa0.y);                                 \
        Aw_[SAH]      = cvt_pk(pa0.z, pa0.w);                                 \
        Aw_[32]       = cvt_pk(pa1.x, pa1.y);                                 \
        Aw_[SAH + 32] = cvt_pk(pa1.z, pa1.w);                                 \
        h2* Bw_ = Bsh + (buf) * BSZ + 2 * akc * SBH + awr;                    \
        Bw_[0]        = cvt_pk(pb0.x, pb0.y);                                 \
        Bw_[SBH]      = cvt_pk(pb0.z, pb0.w);                                 \
    } while (0)

#define COMPUTE(buf) do {                                                     \
        _Pragma("unroll")                                                     \
        for (int s = 0; s < 8; ++s) {                                         \
            const int u_ = s >> 1, o_ = s & 1;                                \
            const h8 a_ = *(const h8*)(Ash + (buf) * ASZ + aoff[u_] + o_ * SAH); \
            const h8 b_ = *(const h8*)(Bsh + (buf) * BSZ + boff[u_] + o_ * SBH); \
            const h2 am[4] = {__builtin_shufflevector(a_, a_, 0, 1),          \
                              __builtin_shufflevector(a_, a_, 2, 3),          \
                              __builtin_shufflevector(a_, a_, 4, 5),          \
                              __builtin_shufflevector(a_, a_, 6, 7)};         \
            const h2 bn[4] = {__builtin_shufflevector(b_, b_, 0, 1),          \
                              __builtin_shufflevector(b_, b_, 2, 3),          \
                              __builtin_shufflevector(b_, b_, 4, 5),          \
                              __builtin_shufflevector(b_, b_, 6, 7)};         \
            _Pragma("unroll")                                                 \
            for (int i_ = 0; i_ < 4; ++i_)                                    \
            {                                                                 \
                _Pragma("unroll")                                             \
                for (int j_ = 0; j_ < 4; ++j_) {                              \
                    const h2 p_ = am[i_] * bn[j_];                            \
                    pmax[i_][j_] = h2max(pmax[i_][j_], p_);                   \
                    pmin[i_][j_] = h2min(pmin[i_][j_], p_);                   \
                }                                                             \
            }                                                                 \
        }                                                                     \
    } while (0)

    // ---- main loop: double-buffered, one barrier per tile ----
    GLOAD(0);
    SWRITE(0);
    __syncthreads();

#pragma unroll 1
    for (int ktt = 0; ktt < NTILES / 2 - 1; ++ktt) {
        GLOAD(2 * ktt + 1);
        COMPUTE(0);
        SWRITE(1);
        __syncthreads();
        GLOAD(2 * ktt + 2);
        COMPUTE(1);
        SWRITE(0);
        __syncthreads();
    }
    GLOAD(NTILES - 1);
    COMPUTE(0);
    SWRITE(1);
    __syncthreads();
    COMPUTE(1);

    // ---- epilogue: 2-round tree combine across the 4 k-groups ----
#define EPI_PACK(dst) do {                                                    \
        float* w_ = (dst);                                                    \
        _Pragma("unroll")                                                     \
        for (int i_ = 0; i_ < 4; ++i_) {                                      \
            float4 vx_, vn_;                                                  \
            vx_.x = __builtin_bit_cast(float, pmax[i_][0]);                   \
            vx_.y = __builtin_bit_cast(float, pmax[i_][1]);                   \
            vx_.z = __builtin_bit_cast(float, pmax[i_][2]);                   \
            vx_.w = __builtin_bit_cast(float, pmax[i_][3]);                   \
            vn_.x = __builtin_bit_cast(float, pmin[i_][0]);                   \
            vn_.y = __builtin_bit_cast(float, pmin[i_][1]);                   \
            vn_.z = __builtin_bit_cast(float, pmin[i_][2]);                   \
            vn_.w = __builtin_bit_cast(float, pmin[i_][3]);                   \
            *(float4*)(w_ + i_ * 4)      = vx_;                               \
            *(float4*)(w_ + 16 + i_ * 4) = vn_;                               \
        }                                                                     \
    } while (0)

#define EPI_COMBINE(src) do {                                                 \
        const float* r_ = (src);                                              \
        _Pragma("unroll")                                                     \
        for (int i_ = 0; i_ < 4; ++i_) {                                      \
            const float4 vx_ = *(const float4*)(r_ + i_ * 4);                 \
            const float4 vn_ = *(const float4*)(r_ + 16 + i_ * 4);            \
            pmax[i_][0] = h2max(pmax[i_][0], __builtin_bit_cast(h2, vx_.x));  \
            pmax[i_][1] = h2max(pmax[i_][1], __builtin_bit_cast(h2, vx_.y));  \
            pmax[i_][2] = h2max(pmax[i_][2], __builtin_bit_cast(h2, vx_.z));  \
            pmax[i_][3] = h2max(pmax[i_][3], __builtin_bit_cast(h2, vx_.w));  \
            pmin[i_][0] = h2min(pmin[i_][0], __builtin_bit_cast(h2, vn_.x));  \
            pmin[i_][1] = h2min(pmin[i_][1], __builtin_bit_cast(h2, vn_.y));  \
            pmin[i_][2] = h2min(pmin[i_][2], __builtin_bit_cast(h2, vn_.z));  \
            pmin[i_][3] = h2min(pmin[i_][3], __builtin_bit_cast(h2, vn_.w));  \
        }                                                                     \
    } while (0)

    __syncthreads();                      // staging reads done; safe to alias
    if (g >= 2) EPI_PACK(epi + (size_t)(g - 2) * EPI_REGION + lid * EPI_STRIDE);
    __syncthreads();
    if (g < 2)  EPI_COMBINE(epi + (size_t)g * EPI_REGION + lid * EPI_STRIDE);
    __syncthreads();
    if (g == 1) EPI_PACK(epi + lid * EPI_STRIDE);
    __syncthreads();
    if (g == 0) {
        EPI_COMBINE(epi + lid * EPI_STRIDE);
#pragma unroll
        for (int i = 0; i < 4; ++i) {
            float4 o;
            o.x = fmaxf((float)pmax[i][0].x, (float)pmax[i][0].y)
                + fminf((float)pmin[i][0].x, (float)pmin[i][0].y) + bv.x;
            o.y = fmaxf((float)pmax[i][1].x, (float)pmax[i][1].y)
                + fminf((float)pmin[i][1].x, (float)pmin[i][1].y) + bv.y;
            o.z = fmaxf((float)pmax[i][2].x, (float)pmax[i][2].y)
                + fminf((float)pmin[i][2].x, (float)pmin[i][2].y) + bv.z;
            o.w = fmaxf((float)pmax[i][3].x, (float)pmax[i][3].y)
                + fminf((float)pmin[i][3].x, (float)pmin[i][3].y) + bv.w;
            *(float4*)&out[(size_t)(m0 + mt * 4 + i) * N_DIM + n0 + nt * 4] = o;
        }
    }
}

extern "C" void kernel_launch(void* const* d_in, const int* in_sizes, int n_in,
                              void* d_out, int out_size, void* d_ws, size_t ws_size,
                              hipStream_t stream) {
    const float* x    = (const float*)d_in[0];   // [2,1024,768] -> [2048,768]
    const float* w    = (const float*)d_in[1];   // [768,768] row-major [N][K]
    const float* bias = (const float*)d_in[2];   // [768]
    float* out = (float*)d_out;                  // [2048,768]

    dim3 grid(N_DIM / BN, M_DIM / BM);           // (24, 32) = 768 blocks = 3/CU
    mam_kernel<<<grid, 512, 0, stream>>>(x, w, bias, out);
}

// Round 10
// 75.254 us; speedup vs baseline: 1.1635x; 1.1635x over previous
//
#include <hip/hip_runtime.h>
#include <math.h>

// MAM dense: C[i,j] = max_k(A[i,k]*W[j,k]) + min_k(A[i,k]*W[j,k]) + bias[j]
// A = x flat [M=2048, K=768]; W [N=768, K=768] row-major; out [M,N] f32.
// fp16 packed math (pk_mul/pk_max/pk_min = 3 VALU per 2 products = floor).
// This round: TM4xTN4 (2x ds_read_b128 per 16 outputs -> LDS pipe = VALU floor)
// + split-K x4 (grid 1536 = 6 blocks/CU = 6 waves/SIMD) with packed-f16 partials
// in d_ws and a streaming combine kernel. Spill-proofing: no lambdas, no offset
// arrays, named staging regs, GLOAD after COMPUTE (staging regs never overlap
// compute peak). XOR col-swizzle: LDS writes 2-way (free), reads broadcast.

#define M_DIM 2048
#define N_DIM 768
#define K_DIM 768
#define NOUT (M_DIM * N_DIM)   // 1572864

#define BM 64
#define BN 64
#define BK 64
#define KP 32                  // k-pair rows per tile
#define SAH 68                 // A row stride, h2 units (68*4B -> b128 aligned)
#define SBH 68

typedef _Float16 h2 __attribute__((ext_vector_type(2)));   // 4 B
typedef _Float16 h8 __attribute__((ext_vector_type(8)));   // 16 B

__device__ __forceinline__ h2 cvt_pk(float x, float y) {
    return __builtin_bit_cast(h2, __builtin_amdgcn_cvt_pkrtz(x, y));
}
__device__ __forceinline__ h2 h2max(h2 a, h2 b) { return __builtin_elementwise_max(a, b); }
__device__ __forceinline__ h2 h2min(h2 a, h2 b) { return __builtin_elementwise_min(a, b); }
// pack (max of even/odd maxes, min of even/odd mins) into one u32
__device__ __forceinline__ unsigned packmm(h2 px, h2 pn) {
    h2 r;
    r.x = px.x >= px.y ? px.x : px.y;
    r.y = pn.x <= pn.y ? pn.x : pn.y;
    return __builtin_bit_cast(unsigned, r);
}

template <int NSPL>
__global__ __launch_bounds__(256, 6) void mam_main(
    const float* __restrict__ A, const float* __restrict__ W,
    const float* __restrict__ bias, float* __restrict__ out,
    unsigned* __restrict__ ws)
{
    __shared__ __align__(16) h2 As[KP * SAH];   // 8704 B
    __shared__ __align__(16) h2 Bs[KP * SBH];   // 8704 B

    const int tid = threadIdx.x;
    const int m0  = blockIdx.y * BM;
    const int n0  = blockIdx.x * BN;
    const int NT  = 12 / NSPL;                  // k-tiles this block owns
    const int kb  = blockIdx.z * NT * BK;

    const int mt  = tid >> 4;                   // 0..15 -> rows 4mt..4mt+3
    const int nt  = tid & 15;                   // 0..15 -> cols 4nt..4nt+3
    const int am4 = 4 * mt;                     // A read col base (h2 units)
    const int bn4 = 4 * nt;

    h2 pmax[4][4], pmin[4][4];
    const _Float16 HMIN = (_Float16)(-65504.0f), HMAX = (_Float16)(65504.0f);
#pragma unroll
    for (int i = 0; i < 4; ++i)
#pragma unroll
        for (int j = 0; j < 4; ++j) {
            pmax[i][j] = (h2){HMIN, HMIN};
            pmin[i][j] = (h2){HMAX, HMAX};
        }

    // staging: thread -> rows arow+{0,16,32,48}, k-chunk akc (k = akc*4)
    const int arow = tid >> 4;                  // 0..15
    const int akc  = tid & 15;                  // kk2 rows 2akc, 2akc+1
    const int swz  = 4 * (akc & 7);             // XOR col swizzle (bits 2..4)
    const float* Ap = A + (size_t)(m0 + arow) * K_DIM + kb + akc * 4;
    const float* Wp = W + (size_t)(n0 + arow) * K_DIM + kb + akc * 4;

    float4 pa0, pa1, pa2, pa3, pb0, pb1, pb2, pb3;

#define GLOAD(t) do {                                                        \
        const float* An_ = Ap + (t) * BK;                                    \
        const float* Wn_ = Wp + (t) * BK;                                    \
        pa0 = *(const float4*)(An_ + (size_t) 0 * K_DIM);                    \
        pa1 = *(const float4*)(An_ + (size_t)16 * K_DIM);                    \
        pa2 = *(const float4*)(An_ + (size_t)32 * K_DIM);                    \
        pa3 = *(const float4*)(An_ + (size_t)48 * K_DIM);                    \
        pb0 = *(const float4*)(Wn_ + (size_t) 0 * K_DIM);                    \
        pb1 = *(const float4*)(Wn_ + (size_t)16 * K_DIM);                    \
        pb2 = *(const float4*)(Wn_ + (size_t)32 * K_DIM);                    \
        pb3 = *(const float4*)(Wn_ + (size_t)48 * K_DIM);                    \
    } while (0)

#define SWRITE() do {                                                        \
        h2* Aw_ = As + 2 * akc * SAH;                                        \
        h2* Bw_ = Bs + 2 * akc * SBH;                                        \
        const int c0_ = (arow +  0) ^ swz;                                   \
        const int c1_ = (arow + 16) ^ swz;                                   \
        const int c2_ = (arow + 32) ^ swz;                                   \
        const int c3_ = (arow + 48) ^ swz;                                   \
        Aw_[c0_]       = cvt_pk(pa0.x, pa0.y);                               \
        Aw_[SAH + c0_] = cvt_pk(pa0.z, pa0.w);                               \
        Aw_[c1_]       = cvt_pk(pa1.x, pa1.y);                               \
        Aw_[SAH + c1_] = cvt_pk(pa1.z, pa1.w);                               \
        Aw_[c2_]       = cvt_pk(pa2.x, pa2.y);                               \
        Aw_[SAH + c2_] = cvt_pk(pa2.z, pa2.w);                               \
        Aw_[c3_]       = cvt_pk(pa3.x, pa3.y);                               \
        Aw_[SAH + c3_] = cvt_pk(pa3.z, pa3.w);                               \
        Bw_[c0_]       = cvt_pk(pb0.x, pb0.y);                               \
        Bw_[SBH + c0_] = cvt_pk(pb0.z, pb0.w);                               \
        Bw_[c1_]       = cvt_pk(pb1.x, pb1.y);                               \
        Bw_[SBH + c1_] = cvt_pk(pb1.z, pb1.w);                               \
        Bw_[c2_]       = cvt_pk(pb2.x, pb2.y);                               \
        Bw_[SBH + c2_] = cvt_pk(pb2.z, pb2.w);                               \
        Bw_[c3_]       = cvt_pk(pb3.x, pb3.y);                               \
        Bw_[SBH + c3_] = cvt_pk(pb3.z, pb3.w);                               \
    } while (0)

    // reads: data col m' sits at LDS col m' ^ (4*((kk2>>1)&7)); XOR by mult
    // of 4 preserves b128 contiguity. A: 4 addrs/wave (16-way bcast);
    // B: 16 addrs, 2-way bank alias = free.
#define COMPUTE() do {                                                       \
        _Pragma("unroll")                                                    \
        for (int kk2 = 0; kk2 < KP; ++kk2) {                                 \
            const int cc_ = 4 * ((kk2 >> 1) & 7);                            \
            const h8 a_ = *(const h8*)(As + kk2 * SAH + (am4 ^ cc_));        \
            const h8 b_ = *(const h8*)(Bs + kk2 * SBH + (bn4 ^ cc_));        \
            const h2 am0 = __builtin_shufflevector(a_, a_, 0, 1);            \
            const h2 am1 = __builtin_shufflevector(a_, a_, 2, 3);            \
            const h2 am2 = __builtin_shufflevector(a_, a_, 4, 5);            \
            const h2 am3 = __builtin_shufflevector(a_, a_, 6, 7);            \
            const h2 bn0 = __builtin_shufflevector(b_, b_, 0, 1);            \
            const h2 bn1 = __builtin_shufflevector(b_, b_, 2, 3);            \
            const h2 bn2 = __builtin_shufflevector(b_, b_, 4, 5);            \
            const h2 bn3 = __builtin_shufflevector(b_, b_, 6, 7);            \
            h2 p_;                                                           \
            p_ = am0 * bn0; pmax[0][0] = h2max(pmax[0][0], p_); pmin[0][0] = h2min(pmin[0][0], p_); \
            p_ = am0 * bn1; pmax[0][1] = h2max(pmax[0][1], p_); pmin[0][1] = h2min(pmin[0][1], p_); \
            p_ = am0 * bn2; pmax[0][2] = h2max(pmax[0][2], p_); pmin[0][2] = h2min(pmin[0][2], p_); \
            p_ = am0 * bn3; pmax[0][3] = h2max(pmax[0][3], p_); pmin[0][3] = h2min(pmin[0][3], p_); \
            p_ = am1 * bn0; pmax[1][0] = h2max(pmax[1][0], p_); pmin[1][0] = h2min(pmin[1][0], p_); \
            p_ = am1 * bn1; pmax[1][1] = h2max(pmax[1][1], p_); pmin[1][1] = h2min(pmin[1][1], p_); \
            p_ = am1 * bn2; pmax[1][2] = h2max(pmax[1][2], p_); pmin[1][2] = h2min(pmin[1][2], p_); \
            p_ = am1 * bn3; pmax[1][3] = h2max(pmax[1][3], p_); pmin[1][3] = h2min(pmin[1][3], p_); \
            p_ = am2 * bn0; pmax[2][0] = h2max(pmax[2][0], p_); pmin[2][0] = h2min(pmin[2][0], p_); \
            p_ = am2 * bn1; pmax[2][1] = h2max(pmax[2][1], p_); pmin[2][1] = h2min(pmin[2][1], p_); \
            p_ = am2 * bn2; pmax[2][2] = h2max(pmax[2][2], p_); pmin[2][2] = h2min(pmin[2][2], p_); \
            p_ = am2 * bn3; pmax[2][3] = h2max(pmax[2][3], p_); pmin[2][3] = h2min(pmin[2][3], p_); \
            p_ = am3 * bn0; pmax[3][0] = h2max(pmax[3][0], p_); pmin[3][0] = h2min(pmin[3][0], p_); \
            p_ = am3 * bn1; pmax[3][1] = h2max(pmax[3][1], p_); pmin[3][1] = h2min(pmin[3][1], p_); \
            p_ = am3 * bn2; pmax[3][2] = h2max(pmax[3][2], p_); pmin[3][2] = h2min(pmin[3][2], p_); \
            p_ = am3 * bn3; pmax[3][3] = h2max(pmax[3][3], p_); pmin[3][3] = h2min(pmin[3][3], p_); \
        }                                                                    \
    } while (0)

    // schedule: GLOAD after COMPUTE so staging regs never overlap compute peak
    GLOAD(0);
    SWRITE();
    __syncthreads();
#pragma unroll 1
    for (int t = 0; t < NT - 1; ++t) {
        COMPUTE();
        GLOAD(t + 1);          // issue; latency overlaps barrier + other waves
        __syncthreads();       // all waves done reading As/Bs
        SWRITE();              // waits own vmcnt
        __syncthreads();
    }
    COMPUTE();

    if (NSPL == 1) {
        const float4 bv = *(const float4*)(bias + n0 + bn4);
#pragma unroll
        for (int i = 0; i < 4; ++i) {
            float4 o;
            o.x = fmaxf((float)pmax[i][0].x, (float)pmax[i][0].y)
                + fminf((float)pmin[i][0].x, (float)pmin[i][0].y) + bv.x;
            o.y = fmaxf((float)pmax[i][1].x, (float)pmax[i][1].y)
                + fminf((float)pmin[i][1].x, (float)pmin[i][1].y) + bv.y;
            o.z = fmaxf((float)pmax[i][2].x, (float)pmax[i][2].y)
                + fminf((float)pmin[i][2].x, (float)pmin[i][2].y) + bv.z;
            o.w = fmaxf((float)pmax[i][3].x, (float)pmax[i][3].y)
                + fminf((float)pmin[i][3].x, (float)pmin[i][3].y) + bv.w;
            *(float4*)&out[(size_t)(m0 + am4 + i) * N_DIM + n0 + bn4] = o;
        }
    } else {
        unsigned* wp = ws + (size_t)blockIdx.z * NOUT
                          + (size_t)(m0 + am4) * N_DIM + n0 + bn4;
#pragma unroll
        for (int i = 0; i < 4; ++i) {
            uint4 v;
            v.x = packmm(pmax[i][0], pmin[i][0]);
            v.y = packmm(pmax[i][1], pmin[i][1]);
            v.z = packmm(pmax[i][2], pmin[i][2]);
            v.w = packmm(pmax[i][3], pmin[i][3]);
            *(uint4*)(wp + (size_t)i * N_DIM) = v;
        }
    }
}

// streaming combine: out = max(4 pmax) + min(4 pmin) + bias; 31.5 MB traffic
__global__ __launch_bounds__(256) void mam_combine(
    const unsigned* __restrict__ ws, const float* __restrict__ bias,
    float* __restrict__ out)
{
    const int i4 = (blockIdx.x * 256 + threadIdx.x) * 4;   // grid covers NOUT exactly
    const uint4 v0 = *(const uint4*)(ws + (size_t)0 * NOUT + i4);
    const uint4 v1 = *(const uint4*)(ws + (size_t)1 * NOUT + i4);
    const uint4 v2 = *(const uint4*)(ws + (size_t)2 * NOUT + i4);
    const uint4 v3 = *(const uint4*)(ws + (size_t)3 * NOUT + i4);
    const float4 bv = *(const float4*)(bias + (i4 % N_DIM));
    float4 o;
#define CMB(e) do {                                                          \
        const h2 a_ = __builtin_bit_cast(h2, v0.e);                          \
        const h2 b_ = __builtin_bit_cast(h2, v1.e);                          \
        const h2 c_ = __builtin_bit_cast(h2, v2.e);                          \
        const h2 d_ = __builtin_bit_cast(h2, v3.e);                          \
        const h2 mx_ = h2max(h2max(a_, b_), h2max(c_, d_));                  \
        const h2 mn_ = h2min(h2min(a_, b_), h2min(c_, d_));                  \
        o.e = (float)mx_.x + (float)mn_.y + bv.e;                            \
    } while (0)
    CMB(x); CMB(y); CMB(z); CMB(w);
#undef CMB
    *(float4*)(out + i4) = o;
}

extern "C" void kernel_launch(void* const* d_in, const int* in_sizes, int n_in,
                              void* d_out, int out_size, void* d_ws, size_t ws_size,
                              hipStream_t stream) {
    const float* x    = (const float*)d_in[0];   // [2,1024,768] -> [2048,768]
    const float* w    = (const float*)d_in[1];   // [768,768] row-major [N][K]
    const float* bias = (const float*)d_in[2];   // [768]
    float* out = (float*)d_out;                  // [2048,768]

    const size_t need = (size_t)4 * NOUT * sizeof(unsigned);   // 25.2 MB
    if (ws_size >= need) {
        // split-K x4: 1536 blocks = 6/CU = 6 waves/SIMD
        mam_main<4><<<dim3(N_DIM / BN, M_DIM / BM, 4), 256, 0, stream>>>(
            x, w, bias, out, (unsigned*)d_ws);
        mam_combine<<<NOUT / 4 / 256, 256, 0, stream>>>(
            (const unsigned*)d_ws, bias, out);
    } else {
        // fallback: single kernel, full K per block (384 blocks)
        mam_main<1><<<dim3(N_DIM / BN, M_DIM / BM, 1), 256, 0, stream>>>(
            x, w, bias, out, nullptr);
    }
}